// Round 10
// baseline (1328.075 us; speedup 1.0000x reference)
//
#include <hip/hip_runtime.h>
#include <math.h>

#define TOKENS 16384
#define HIDDEN 7168
#define NEXP   256
#define TOPK   8
#define KS     64
#define NSTEP  (HIDDEN / KS)      // 112
#define TPB    16                 // tokens per block -> 1024 blocks
#define SMEM_MAIN (1024 + 16 * 257 * 4)   // bias + score plane = 17472 (no K-loop LDS)
#define BSTEP  (4 * NEXP * 64)    // 65536 B per k-step slice of B limbs

typedef __attribute__((ext_vector_type(4))) int i32x4;

// B limb layout: byte addr = ((s*4 + p)*256 + n)*64 + k'  (slice s, limb p, expert n, k')
// total 112*4*256*64 = 7,340,032 B in d_ws

// ---------------------------------------------------------------------------
// prep: W[256][7168] fp32 -> 4 signed-digit int8 limb planes of round(w * 2^31)
// (bit-identical to the harness-verified kernel)
// ---------------------------------------------------------------------------
__global__ __launch_bounds__(256) void prep_b(const float* __restrict__ w, char* __restrict__ bl)
{
    const int g = blockIdx.x * 256 + threadIdx.x;   // 448*256 threads, 16 elems each
    const int e = g * 16;
    const int n = e / HIDDEN;
    const int k = e % HIDDEN;
    const int s = k >> 6;
    const int kc = (k >> 4) & 3;
    unsigned pk[4][4];   // [limb][4-elem group]
#pragma unroll
    for (int grp = 0; grp < 4; ++grp) {
        const float4 v = *(const float4*)(w + e + grp * 4);
        const float xs[4] = {v.x, v.y, v.z, v.w};
        unsigned a0 = 0, a1 = 0, a2 = 0, a3 = 0;
#pragma unroll
        for (int c = 0; c < 4; ++c) {
            const int X  = (int)rintf(xs[c] * 2147483648.0f);  // w * 2^31 (|X| < 2.5e8)
            const int X1 = (X  + 128) >> 8;                    // signed base-256 digits
            const int X2 = (X1 + 128) >> 8;
            const int X3 = (X2 + 128) >> 8;
            a0 |= (unsigned)((X  - (X1 << 8)) & 255) << (8 * c);
            a1 |= (unsigned)((X1 - (X2 << 8)) & 255) << (8 * c);
            a2 |= (unsigned)((X2 - (X3 << 8)) & 255) << (8 * c);
            a3 |= (unsigned)( X3              & 255) << (8 * c);
        }
        pk[0][grp] = a0; pk[1][grp] = a1; pk[2][grp] = a2; pk[3][grp] = a3;
    }
#pragma unroll
    for (int p = 0; p < 4; ++p) {
        i32x4 d = {(int)pk[p][0], (int)pk[p][1], (int)pk[p][2], (int)pk[p][3]};
        *(i32x4*)(bl + (((size_t)(s * 4 + p) * NEXP + n) * 64 + kc * 16)) = d;
    }
}

// ---------------------------------------------------------------------------
// main: exact 4-limb i8 MFMA GEMM (pa+pb>=2 -> 13 MFMA/tile, bit-identical
//       numerics to the verified kernel), 16 tok x 256 experts / WG,
//       BARRIER-FREE K-loop:
//  - each lane loads+converts its OWN A fragment (row=lane&15, k=q*16..+15)
//    -> no LDS staging, no __syncthreads in the loop -> no vmcnt(0) drains,
//    waves desync freely. 13-MFMA cluster (~265 cyc) > L2-hit latency
//    (~200 cyc) -> single-wave ILP covers the pipelined next-j B loads.
//    (Round-3 lockstep barrier+LDS version stalled everything at ~20%.)
//  - conversion VALU (~384 cyc/step) co-issues against 1060 MFMA cyc/step.
//  - acc[5][4]=80 regs; ~160 live total -> launch_bounds(256,3).
// ---------------------------------------------------------------------------
__global__ __launch_bounds__(256, 3) void router_main(
        const float* __restrict__ Xg,
        const float* __restrict__ bias,
        const char* __restrict__ BL,
        float* __restrict__ outI,
        float* __restrict__ outW)
{
    extern __shared__ char smem[];
    float* biasL = (float*)smem;                  // [256] f32
    float* plane = (float*)(smem + 1024);         // [16][257] f32 scores

    const int tid  = threadIdx.x;
    const int b    = blockIdx.x;
    const int wave = tid >> 6;
    const int lane = tid & 63;
    const int l15  = lane & 15;
    const int q    = lane >> 4;

    biasL[tid] = bias[tid];

    // per-lane A source: token row l15, k-chunk q*16 (16 consecutive floats)
    const float* aptr = Xg + (size_t)(b * TPB + l15) * HIDDEN + q * 16;
    // per-lane B source offset within a step slice (expert wave*64+j*16+l15)
    const int boff = (wave * 64 + l15) * 64 + q * 16;

    i32x4 acc[5][4];
#pragma unroll
    for (int t = 0; t < 5; ++t)
#pragma unroll
        for (int j = 0; j < 4; ++j)
            acc[t][j] = (i32x4){0, 0, 0, 0};

// convert 4 floats of vf into word g of the four A-limb fragments (x * 2^28)
#define CVT4(vf, g)                                                           \
    {                                                                         \
        const float cx[4] = {vf.x, vf.y, vf.z, vf.w};                         \
        unsigned c0 = 0, c1 = 0, c2 = 0, c3 = 0;                              \
        _Pragma("unroll")                                                     \
        for (int c = 0; c < 4; ++c) {                                         \
            const int X  = (int)rintf(cx[c] * 268435456.0f);  /* x * 2^28 */  \
            const int X1 = (X  + 128) >> 8;                                   \
            const int X2 = (X1 + 128) >> 8;                                   \
            const int X3 = (X2 + 128) >> 8;                                   \
            c0 |= (unsigned)((X  - (X1 << 8)) & 255) << (8 * c);              \
            c1 |= (unsigned)((X1 - (X2 << 8)) & 255) << (8 * c);              \
            c2 |= (unsigned)((X2 - (X3 << 8)) & 255) << (8 * c);              \
            c3 |= (unsigned)( X3              & 255) << (8 * c);              \
        }                                                                     \
        af0[g] = (int)c0; af1[g] = (int)c1; af2[g] = (int)c2; af3[g] = (int)c3; \
    }

#define LOADB(dst, base, jj)                                                  \
    dst[0] = *(const i32x4*)((base) + 0 * 16384 + (jj) * 1024);               \
    dst[1] = *(const i32x4*)((base) + 1 * 16384 + (jj) * 1024);               \
    dst[2] = *(const i32x4*)((base) + 2 * 16384 + (jj) * 1024);               \
    dst[3] = *(const i32x4*)((base) + 3 * 16384 + (jj) * 1024);

// 13 MFMA: all (pa,pb) with pa+pb>=2 -> acc[pa+pb-2]; acc chains interleaved
#define MFMA13(jj, B)                                                         \
    acc[0][jj] = __builtin_amdgcn_mfma_i32_16x16x64_i8(af0, B[2], acc[0][jj], 0, 0, 0); \
    acc[1][jj] = __builtin_amdgcn_mfma_i32_16x16x64_i8(af0, B[3], acc[1][jj], 0, 0, 0); \
    acc[2][jj] = __builtin_amdgcn_mfma_i32_16x16x64_i8(af1, B[3], acc[2][jj], 0, 0, 0); \
    acc[3][jj] = __builtin_amdgcn_mfma_i32_16x16x64_i8(af2, B[3], acc[3][jj], 0, 0, 0); \
    acc[4][jj] = __builtin_amdgcn_mfma_i32_16x16x64_i8(af3, B[3], acc[4][jj], 0, 0, 0); \
    acc[0][jj] = __builtin_amdgcn_mfma_i32_16x16x64_i8(af1, B[1], acc[0][jj], 0, 0, 0); \
    acc[1][jj] = __builtin_amdgcn_mfma_i32_16x16x64_i8(af1, B[2], acc[1][jj], 0, 0, 0); \
    acc[2][jj] = __builtin_amdgcn_mfma_i32_16x16x64_i8(af2, B[2], acc[2][jj], 0, 0, 0); \
    acc[3][jj] = __builtin_amdgcn_mfma_i32_16x16x64_i8(af3, B[2], acc[3][jj], 0, 0, 0); \
    acc[0][jj] = __builtin_amdgcn_mfma_i32_16x16x64_i8(af2, B[0], acc[0][jj], 0, 0, 0); \
    acc[1][jj] = __builtin_amdgcn_mfma_i32_16x16x64_i8(af2, B[1], acc[1][jj], 0, 0, 0); \
    acc[2][jj] = __builtin_amdgcn_mfma_i32_16x16x64_i8(af3, B[1], acc[2][jj], 0, 0, 0); \
    acc[1][jj] = __builtin_amdgcn_mfma_i32_16x16x64_i8(af3, B[0], acc[1][jj], 0, 0, 0);

    // prologue: step-0 A floats + step-0 j=0 B fragments
    float4 xa0 = *(const float4*)(aptr + 0);
    float4 xa1 = *(const float4*)(aptr + 4);
    float4 xa2 = *(const float4*)(aptr + 8);
    float4 xa3 = *(const float4*)(aptr + 12);
    i32x4 bf0[4], bf1[4];
    LOADB(bf0, BL + boff, 0);

    for (int s = 0; s < NSTEP; ++s) {
        // 1. convert step-s A floats to the 4 limb fragments (VALU pipe;
        //    other desynced waves' MFMAs cover this)
        i32x4 af0, af1, af2, af3;
        CVT4(xa0, 0); CVT4(xa1, 1); CVT4(xa2, 2); CVT4(xa3, 3);

        // 2. prefetch step-s+1 A floats (clamped on the last iter)
        const int sn = (s + 1 < NSTEP) ? s + 1 : s;
        {
            const float* ap = aptr + sn * KS;
            xa0 = *(const float4*)(ap + 0);
            xa1 = *(const float4*)(ap + 4);
            xa2 = *(const float4*)(ap + 8);
            xa3 = *(const float4*)(ap + 12);
        }

        // 3. j-phases: 13-MFMA clusters (~265 cyc) with next-j B loads
        //    (L2-hit ~200 cyc) in flight -> self-covering, no barriers
        const char* bb  = BL + (size_t)s * BSTEP + boff;
        const char* bbn = BL + (size_t)sn * BSTEP + boff;
        LOADB(bf1, bb, 1);
        MFMA13(0, bf0);
        LOADB(bf0, bb, 2);
        MFMA13(1, bf1);
        LOADB(bf1, bb, 3);
        MFMA13(2, bf0);
        LOADB(bf0, bbn, 0);     // next step's j=0
        MFMA13(3, bf1);
    }

    // ---- epilogue: exact combine (f64) -> f32 logit -> f32 sigmoid pipeline
    // C/D layout: col = lane&15 (n), row = q*4 + reg (m)
#pragma unroll
    for (int j = 0; j < 4; ++j)
#pragma unroll
        for (int r = 0; r < 4; ++r) {
            const double S = ((((double)acc[4][j][r] * 256.0 + (double)acc[3][j][r]) * 256.0
                              + (double)acc[2][j][r]) * 256.0 + (double)acc[1][j][r]) * 256.0
                              + (double)acc[0][j][r];
            const float lg = (float)(S * 0x1p-43);            // f32 logit (RNE)
            const float e  = (float)exp(-(double)lg);         // correctly-rounded f32 exp
            const float sc = 1.0f / (1.0f + e);               // f32 ops, mirrors np
            plane[(q * 4 + r) * 257 + (wave * 64 + j * 16 + l15)] = sc;
        }
    __syncthreads();   // the ONLY barrier: plane + biasL visible to wave 0

    // ---- routing on f32 values, stable lower-index tie-breaks (1 lane / token)
    if (tid < TPB) {
        const float* row = plane + tid * 257;
        float gs[8];
#pragma unroll
        for (int g = 0; g < 8; ++g) {                  // per-group top-2 sum (f32)
            float m1 = -1e30f, m2 = -1e30f;
            for (int k = 0; k < 32; ++k) {
                const float v = row[g * 32 + k] + biasL[g * 32 + k];
                if (v > m1) { m2 = m1; m1 = v; }
                else if (v > m2) { m2 = v; }
            }
            gs[g] = m1 + m2;                           // descending-order f32 add
        }
        unsigned gmask = 0;                            // top-4 groups, stable
#pragma unroll
        for (int rs = 0; rs < 4; ++rs) {
            float best = -1e30f; int bg = 0;
            for (int g = 0; g < 8; ++g)
                if (!((gmask >> g) & 1) && gs[g] > best) { best = gs[g]; bg = g; }
            gmask |= 1u << bg;
        }
        float tv[8]; int ti[8];                        // stable top-8, masked = 0.0f
#pragma unroll
        for (int j = 0; j < 8; ++j) { tv[j] = -1e30f; ti[j] = 0; }
        for (int e = 0; e < 256; ++e) {
            const float v = ((gmask >> (e >> 5)) & 1) ? (row[e] + biasL[e]) : 0.0f;
            if (v > tv[7]) {
                int p = 7;
                while (p > 0 && v > tv[p - 1]) { tv[p] = tv[p - 1]; ti[p] = ti[p - 1]; --p; }
                tv[p] = v; ti[p] = e;
            }
        }
        float sum = 0.f, wv[8];
#pragma unroll
        for (int j = 0; j < 8; ++j) { wv[j] = row[ti[j]]; sum += wv[j]; }  // raw f32 sigmoid
        const float denom = sum + 1e-20f;
        const size_t o = ((size_t)b * TPB + tid) * TOPK;
#pragma unroll
        for (int j = 0; j < 8; ++j) {
            outI[o + j] = (float)ti[j];
            outW[o + j] = wv[j] / denom * 2.5f;
        }
    }
#undef LOADB
#undef MFMA13
#undef CVT4
}

// ---------------------------------------------------------------------------
extern "C" void kernel_launch(void* const* d_in, const int* in_sizes, int n_in,
                              void* d_out, int out_size, void* d_ws, size_t ws_size,
                              hipStream_t stream)
{
    const float* X    = (const float*)d_in[0];
    const float* W    = (const float*)d_in[1];
    const float* bias = (const float*)d_in[2];

    char* BL = (char*)d_ws;                            // 7,340,032 B limb planes
    float* outI = (float*)d_out;
    float* outW = outI + (size_t)TOKENS * TOPK;

    prep_b<<<448, 256, 0, stream>>>(W, BL);
    router_main<<<TOKENS / TPB, 256, SMEM_MAIN, stream>>>(X, bias, BL, outI, outW);
}